// Round 6
// baseline (1121.038 us; speedup 1.0000x reference)
//
#include <hip/hip_runtime.h>
#include <hip/hip_fp16.h>
#include <math.h>

#define NNODES 100000
#define NEDGES 3200000
#define NGRAPHS 512
#define NREP 8                      // one kv replica per XCD
#define REPSTRIDE ((size_t)NNODES * 64)   // halves per replica (max-D layout)

// ---------- CSR build ----------

__global__ void csr_init_kernel(int* __restrict__ cnt,
                                float* __restrict__ pool, float* __restrict__ counts) {
    int i = blockIdx.x * blockDim.x + threadIdx.x;
    if (i < NNODES) cnt[i] = 0;
    if (i < NGRAPHS * 32) pool[i] = 0.0f;
    if (i < NGRAPHS) counts[i] = 0.0f;
}

__global__ void count_deg_kernel(const int* __restrict__ ei, int* __restrict__ cnt) {
    int e = blockIdx.x * blockDim.x + threadIdx.x;
    if (e >= NEDGES) return;
    atomicAdd(cnt + ei[NEDGES + e], 1);
}

__global__ void scan_kernel(const int* __restrict__ cnt, int* __restrict__ rowptr,
                            int* __restrict__ cursor) {
    __shared__ int ssum[1024];
    const int CH = (NNODES + 1023) / 1024;
    int t = threadIdx.x;
    int base = t * CH;
    int local = 0;
    for (int i = 0; i < CH; ++i) {
        int idx = base + i;
        if (idx < NNODES) local += cnt[idx];
    }
    ssum[t] = local;
    __syncthreads();
    for (int o = 1; o < 1024; o <<= 1) {
        int vv = (t >= o) ? ssum[t - o] : 0;
        __syncthreads();
        ssum[t] += vv;
        __syncthreads();
    }
    int run = (t > 0) ? ssum[t - 1] : 0;
    for (int i = 0; i < CH; ++i) {
        int idx = base + i;
        if (idx < NNODES) {
            rowptr[idx] = run;
            cursor[idx] = run;
            run += cnt[idx];
        }
    }
    if (t == 1023) rowptr[NNODES] = ssum[1023];
}

__global__ void scatter_kernel(const int* __restrict__ ei, int* __restrict__ cursor,
                               int* __restrict__ col) {
    int e = blockIdx.x * blockDim.x + threadIdx.x;
    if (e >= NEDGES) return;
    int s = ei[e];
    int d = ei[NEDGES + e];
    int pos = atomicAdd(cursor + d, 1);
    col[pos] = s;
}

// ---------- fused 4x linear: q (f32), kv interleaved (f16, 8 replicas), skip ----------
// kv row layout (per node, 2*DOUT halves): channel-quad g4 = j/4 owns
// halves [g4*8 .. g4*8+7] = [k_{4g4..4g4+3} | v_{4g4..4g4+3}], so a gather
// lane reads its k-quad AND v-quad in ONE 16B load. The row is written to
// NREP identical replicas so each XCD's gather blocks can hit their own L2.

template<int DIN, int DOUT>
__global__ void linear4_kernel(const float* __restrict__ x,
                               const float* __restrict__ Wq, const float* __restrict__ bq,
                               const float* __restrict__ Wk, const float* __restrict__ bk,
                               const float* __restrict__ Wv, const float* __restrict__ bv,
                               const float* __restrict__ Ws, const float* __restrict__ bs,
                               float* __restrict__ q, __half* __restrict__ kv,
                               float* __restrict__ s) {
    __shared__ float sW[4][DIN * DOUT];
    __shared__ float sB[4][DOUT];
    const float* Wp[4] = {Wq, Wk, Wv, Ws};
    const float* Bp[4] = {bq, bk, bv, bs};
    for (int m = 0; m < 4; ++m) {
        for (int i = threadIdx.x; i < DIN * DOUT; i += blockDim.x) sW[m][i] = Wp[m][i];
        for (int i = threadIdx.x; i < DOUT; i += blockDim.x) sB[m][i] = Bp[m][i];
    }
    __syncthreads();
    int n = blockIdx.x * blockDim.x + threadIdx.x;
    if (n >= NNODES) return;

    float xr[DIN];
    #pragma unroll
    for (int i = 0; i < DIN; ++i) xr[i] = x[(size_t)n * DIN + i];

    // m=0 -> q (f32), m=1 -> k (f16, interleaved), m=2 -> v (f16, interleaved),
    // m=3 -> skip (f32)
    #pragma unroll
    for (int m = 0; m < 4; ++m) {
        #pragma unroll
        for (int j = 0; j < DOUT; j += 4) {
            float4 acc = make_float4(sB[m][j], sB[m][j + 1], sB[m][j + 2], sB[m][j + 3]);
            #pragma unroll
            for (int i = 0; i < DIN; ++i) {
                float xv = xr[i];
                acc.x += xv * sW[m][i * DOUT + j];
                acc.y += xv * sW[m][i * DOUT + j + 1];
                acc.z += xv * sW[m][i * DOUT + j + 2];
                acc.w += xv * sW[m][i * DOUT + j + 3];
            }
            if (m == 0) {
                *(float4*)(q + (size_t)n * DOUT + j) = acc;
            } else if (m == 3) {
                *(float4*)(s + (size_t)n * DOUT + j) = acc;
            } else {
                // interleaved: quad j/4 at row offset (j/4)*8, k at +0, v at +4
                size_t off = (size_t)n * 2 * DOUT + (size_t)(j >> 2) * 8
                           + (m == 1 ? 0 : 4);
                __half2 h01 = __floats2half2_rn(acc.x, acc.y);
                __half2 h23 = __floats2half2_rn(acc.z, acc.w);
                #pragma unroll
                for (int rp = 0; rp < NREP; ++rp) {
                    __half* op = kv + (size_t)rp * REPSTRIDE + off;
                    *(__half2*)(op)     = h01;
                    *(__half2*)(op + 2) = h23;
                }
            }
        }
    }
}

// ---------- gather attention: TWO nodes per wave, XCD-local kv replica ----------
// Each wave owns two consecutive nodes with independent online-softmax
// chains (2x outstanding requests). kv is read from replica blockIdx&7:
// consecutive blocks round-robin across the 8 XCDs, so each replica's hot
// set stays in its XCD's own L2 (perf heuristic only; replicas identical).

template<int D, bool POOL>
__global__ __launch_bounds__(256) void gather_attn_kernel(
    const int* __restrict__ rowptr, const int* __restrict__ col,
    const float* __restrict__ q, const __half* __restrict__ kv,
    const float* __restrict__ sk, const int* __restrict__ batch,
    float* __restrict__ out, float* __restrict__ pool, float* __restrict__ counts) {
    constexpr int LPE = D / 4;        // lanes per edge
    constexpr int G = 64 / LPE;       // edges per iteration
    int wid = blockIdx.x * 4 + (threadIdx.x >> 6);
    int n0 = wid * 2;
    if (n0 >= NNODES) return;
    int n1 = n0 + 1;                  // NNODES even -> always valid
    int lane = threadIdx.x & 63;
    int l = lane & (LPE - 1);         // channel-quad id
    int g = lane / LPE;               // edge-group id
    const __half* kvb = kv + (size_t)(blockIdx.x & (NREP - 1)) * REPSTRIDE;
    int rs0 = rowptr[n0], rs1 = rowptr[n1], re1 = rowptr[n1 + 1];
    int deg0 = rs1 - rs0, deg1 = re1 - rs1;

    float4 qc0 = *(const float4*)(q + (size_t)n0 * D + 4 * l);
    float4 qc1 = *(const float4*)(q + (size_t)n1 * D + 4 * l);
    float m0 = -INFINITY, den0 = 0.0f, m1 = -INFINITY, den1 = 0.0f;
    float4 A0 = make_float4(0.0f, 0.0f, 0.0f, 0.0f);
    float4 A1 = make_float4(0.0f, 0.0f, 0.0f, 0.0f);
    constexpr float scale = (D == 16) ? 0.25f : 0.17677669529663687f;

    int degmax = max(deg0, deg1);
    for (int off = 0; off < degmax; off += 64) {
        int na0 = min(deg0 - off, 64);   // may be <= 0 (then no active slots)
        int na1 = min(deg1 - off, 64);
        int colv0 = (lane < na0) ? col[rs0 + off + lane] : 0;
        int colv1 = (lane < na1) ? col[rs1 + off + lane] : 0;
        int namax = max(na0, na1);
        int iters = (namax + G - 1) / G;
        for (int it = 0; it < iters; ++it) {
            int slot = it * G + g;
            int src0 = __shfl(colv0, slot, 64);
            int src1 = __shfl(colv1, slot, 64);
            // two independent 16B gathers (node0, node1) in flight together
            uint4 r0 = *(const uint4*)(kvb + (size_t)src0 * (2 * D) + 8 * l);
            uint4 r1 = *(const uint4*)(kvb + (size_t)src1 * (2 * D) + 8 * l);
            bool act0 = slot < na0;
            bool act1 = slot < na1;
            float2 k01a = __half22float2(*(__half2*)&r0.x);
            float2 k23a = __half22float2(*(__half2*)&r0.y);
            float2 v01a = __half22float2(*(__half2*)&r0.z);
            float2 v23a = __half22float2(*(__half2*)&r0.w);
            float2 k01b = __half22float2(*(__half2*)&r1.x);
            float2 k23b = __half22float2(*(__half2*)&r1.y);
            float2 v01b = __half22float2(*(__half2*)&r1.z);
            float2 v23b = __half22float2(*(__half2*)&r1.w);
            float p0 = qc0.x * k01a.x + qc0.y * k01a.y + qc0.z * k23a.x + qc0.w * k23a.y;
            float p1 = qc1.x * k01b.x + qc1.y * k01b.y + qc1.z * k23b.x + qc1.w * k23b.y;
            #pragma unroll
            for (int o = 1; o < LPE; o <<= 1) {
                p0 += __shfl_xor(p0, o, 64);
                p1 += __shfl_xor(p1, o, 64);
            }
            // node0 online-softmax update
            {
                float sc = act0 ? p0 * scale : -INFINITY;
                float mn = fmaxf(m0, sc);
                float r = (mn > m0) ? __expf(m0 - mn) : 1.0f;
                float w = act0 ? __expf(sc - mn) : 0.0f;
                m0 = mn;
                den0 = den0 * r + w;
                A0.x = A0.x * r + w * v01a.x;
                A0.y = A0.y * r + w * v01a.y;
                A0.z = A0.z * r + w * v23a.x;
                A0.w = A0.w * r + w * v23a.y;
            }
            // node1 online-softmax update (independent chain)
            {
                float sc = act1 ? p1 * scale : -INFINITY;
                float mn = fmaxf(m1, sc);
                float r = (mn > m1) ? __expf(m1 - mn) : 1.0f;
                float w = act1 ? __expf(sc - mn) : 0.0f;
                m1 = mn;
                den1 = den1 * r + w;
                A1.x = A1.x * r + w * v01b.x;
                A1.y = A1.y * r + w * v01b.y;
                A1.z = A1.z * r + w * v23b.x;
                A1.w = A1.w * r + w * v23b.y;
            }
        }
    }

    // combine the G edge-groups across lane strides LPE..32, both nodes
    #pragma unroll
    for (int o = LPE; o < 64; o <<= 1) {
        float mo0 = __shfl_xor(m0, o, 64);
        float mo1 = __shfl_xor(m1, o, 64);
        float M0 = fmaxf(m0, mo0);
        float M1 = fmaxf(m1, mo1);
        float r0 = (m0 > -INFINITY) ? __expf(m0 - M0) : 0.0f;
        float r1 = (m1 > -INFINITY) ? __expf(m1 - M1) : 0.0f;
        float ds0 = den0 * r0, ds1 = den1 * r1;
        float a0x = A0.x * r0, a0y = A0.y * r0, a0z = A0.z * r0, a0w = A0.w * r0;
        float a1x = A1.x * r1, a1y = A1.y * r1, a1z = A1.z * r1, a1w = A1.w * r1;
        den0 = ds0 + __shfl_xor(ds0, o, 64);
        den1 = ds1 + __shfl_xor(ds1, o, 64);
        A0.x = a0x + __shfl_xor(a0x, o, 64);
        A0.y = a0y + __shfl_xor(a0y, o, 64);
        A0.z = a0z + __shfl_xor(a0z, o, 64);
        A0.w = a0w + __shfl_xor(a0w, o, 64);
        A1.x = a1x + __shfl_xor(a1x, o, 64);
        A1.y = a1y + __shfl_xor(a1y, o, 64);
        A1.z = a1z + __shfl_xor(a1z, o, 64);
        A1.w = a1w + __shfl_xor(a1w, o, 64);
        m0 = M0;
        m1 = M1;
    }

    if (g == 0) {
        float inv0 = 1.0f / fmaxf(den0, 1e-16f);
        float inv1 = 1.0f / fmaxf(den1, 1e-16f);
        float4 s0 = *(const float4*)(sk + (size_t)n0 * D + 4 * l);
        float4 s1 = *(const float4*)(sk + (size_t)n1 * D + 4 * l);
        float4 o0, o1;
        o0.x = fmaxf(A0.x * inv0 + s0.x, 0.0f);
        o0.y = fmaxf(A0.y * inv0 + s0.y, 0.0f);
        o0.z = fmaxf(A0.z * inv0 + s0.z, 0.0f);
        o0.w = fmaxf(A0.w * inv0 + s0.w, 0.0f);
        o1.x = fmaxf(A1.x * inv1 + s1.x, 0.0f);
        o1.y = fmaxf(A1.y * inv1 + s1.y, 0.0f);
        o1.z = fmaxf(A1.z * inv1 + s1.z, 0.0f);
        o1.w = fmaxf(A1.w * inv1 + s1.w, 0.0f);
        if (POOL) {
            int b0 = batch[n0];
            int b1 = batch[n1];
            atomicAdd(pool + (size_t)b0 * D + 4 * l + 0, o0.x);
            atomicAdd(pool + (size_t)b0 * D + 4 * l + 1, o0.y);
            atomicAdd(pool + (size_t)b0 * D + 4 * l + 2, o0.z);
            atomicAdd(pool + (size_t)b0 * D + 4 * l + 3, o0.w);
            atomicAdd(pool + (size_t)b1 * D + 4 * l + 0, o1.x);
            atomicAdd(pool + (size_t)b1 * D + 4 * l + 1, o1.y);
            atomicAdd(pool + (size_t)b1 * D + 4 * l + 2, o1.z);
            atomicAdd(pool + (size_t)b1 * D + 4 * l + 3, o1.w);
            if (l == 0) {
                atomicAdd(counts + b0, 1.0f);
                atomicAdd(counts + b1, 1.0f);
            }
        } else {
            *(float4*)(out + (size_t)n0 * D + 4 * l) = o0;
            *(float4*)(out + (size_t)n1 * D + 4 * l) = o1;
        }
    }
}

// ---------- FC head ----------

__global__ void final_fc_kernel(const float* __restrict__ pool,
                                const float* __restrict__ counts,
                                const float* __restrict__ Wfc1, const float* __restrict__ bfc1,
                                const float* __restrict__ Wfc2, const float* __restrict__ bfc2,
                                float* __restrict__ out) {
    __shared__ float sW1[32 * 64];
    __shared__ float sB1[64];
    __shared__ float sW2[64];
    for (int i = threadIdx.x; i < 32 * 64; i += blockDim.x) sW1[i] = Wfc1[i];
    for (int i = threadIdx.x; i < 64; i += blockDim.x) { sB1[i] = bfc1[i]; sW2[i] = Wfc2[i]; }
    __syncthreads();
    int g = blockIdx.x * blockDim.x + threadIdx.x;
    if (g >= NGRAPHS) return;
    float c = fmaxf(counts[g], 1.0f);
    float gv[32];
    #pragma unroll
    for (int i = 0; i < 32; ++i) gv[i] = pool[(size_t)g * 32 + i] / c;
    float acc2 = bfc2[0];
    #pragma unroll
    for (int j = 0; j < 64; ++j) {
        float h = sB1[j];
        #pragma unroll
        for (int i = 0; i < 32; ++i) h += gv[i] * sW1[i * 64 + j];
        acc2 += fmaxf(h, 0.0f) * sW2[j];
    }
    out[g] = acc2;
}

// ---------- launch ----------

extern "C" void kernel_launch(void* const* d_in, const int* in_sizes, int n_in,
                              void* d_out, int out_size, void* d_ws, size_t ws_size,
                              hipStream_t stream) {
    const float* x     = (const float*)d_in[0];
    const int*   ei    = (const int*)d_in[1];
    const int*   batch = (const int*)d_in[2];
    const float* Wq1 = (const float*)d_in[3];  const float* bq1 = (const float*)d_in[4];
    const float* Wk1 = (const float*)d_in[5];  const float* bk1 = (const float*)d_in[6];
    const float* Wv1 = (const float*)d_in[7];  const float* bv1 = (const float*)d_in[8];
    const float* Ws1 = (const float*)d_in[9];  const float* bs1 = (const float*)d_in[10];
    const float* Wq2 = (const float*)d_in[11]; const float* bq2 = (const float*)d_in[12];
    const float* Wk2 = (const float*)d_in[13]; const float* bk2 = (const float*)d_in[14];
    const float* Wv2 = (const float*)d_in[15]; const float* bv2 = (const float*)d_in[16];
    const float* Ws2 = (const float*)d_in[17]; const float* bs2 = (const float*)d_in[18];
    const float* Wfc1 = (const float*)d_in[19]; const float* bfc1 = (const float*)d_in[20];
    const float* Wfc2 = (const float*)d_in[21]; const float* bfc2 = (const float*)d_in[22];
    float* out = (float*)d_out;

    char* wsb = (char*)d_ws;
    size_t off = 0;
    auto alloc = [&](size_t bytes) {
        void* p = wsb + off;
        off += (bytes + 255) & ~(size_t)255;
        return p;
    };
    float*  q      = (float*)alloc((size_t)NNODES * 32 * 4);
    __half* kv     = (__half*)alloc(REPSTRIDE * NREP * 2);   // 8 XCD-local replicas
    float*  sk     = (float*)alloc((size_t)NNODES * 32 * 4);
    float*  h1     = (float*)alloc((size_t)NNODES * 16 * 4);
    int*    cnt    = (int*)alloc((size_t)NNODES * 4);
    int*    rowptr = (int*)alloc((size_t)(NNODES + 1) * 4);
    int*    cursor = (int*)alloc((size_t)NNODES * 4);
    int*    col    = (int*)alloc((size_t)NEDGES * 4);
    float*  pool   = (float*)alloc((size_t)NGRAPHS * 32 * 4);
    float*  counts = (float*)alloc((size_t)NGRAPHS * 4);

    const int B = 256;
    const int gridN = (NNODES + B - 1) / B;
    const int gridE = (NEDGES + B - 1) / B;
    const int gridW = (NNODES / 2 + 3) / 4;   // one wave per 2 nodes, 4 waves/block

    // ----- CSR build (by destination), shared by both layers -----
    csr_init_kernel<<<gridN, B, 0, stream>>>(cnt, pool, counts);
    count_deg_kernel<<<gridE, B, 0, stream>>>(ei, cnt);
    scan_kernel<<<1, 1024, 0, stream>>>(cnt, rowptr, cursor);
    scatter_kernel<<<gridE, B, 0, stream>>>(ei, cursor, col);

    // ----- layer 1 (d=16) -----
    linear4_kernel<11, 16><<<gridN, B, 0, stream>>>(x, Wq1, bq1, Wk1, bk1, Wv1, bv1, Ws1, bs1,
                                                    q, kv, sk);
    gather_attn_kernel<16, false><<<gridW, B, 0, stream>>>(rowptr, col, q, kv, sk, batch,
                                                           h1, nullptr, nullptr);

    // ----- layer 2 (d=32) -----
    linear4_kernel<16, 32><<<gridN, B, 0, stream>>>(h1, Wq2, bq2, Wk2, bk2, Wv2, bv2, Ws2, bs2,
                                                    q, kv, sk);
    gather_attn_kernel<32, true><<<gridW, B, 0, stream>>>(rowptr, col, q, kv, sk, batch,
                                                          nullptr, pool, counts);

    // ----- head -----
    final_fc_kernel<<<1, 512, 0, stream>>>(pool, counts, Wfc1, bfc1, Wfc2, bfc2, out);
}

// Round 7
// 1016.232 us; speedup vs baseline: 1.1031x; 1.1031x over previous
//
#include <hip/hip_runtime.h>
#include <hip/hip_fp16.h>
#include <math.h>

#define NNODES 100000
#define NEDGES 3200000
#define NGRAPHS 512

// ---------- CSR build ----------

__global__ void csr_init_kernel(int* __restrict__ cnt,
                                float* __restrict__ pool, float* __restrict__ counts) {
    int i = blockIdx.x * blockDim.x + threadIdx.x;
    if (i < NNODES) cnt[i] = 0;
    if (i < NGRAPHS * 32) pool[i] = 0.0f;
    if (i < NGRAPHS) counts[i] = 0.0f;
}

__global__ void count_deg_kernel(const int* __restrict__ ei, int* __restrict__ cnt) {
    int e = blockIdx.x * blockDim.x + threadIdx.x;
    if (e >= NEDGES) return;
    atomicAdd(cnt + ei[NEDGES + e], 1);
}

__global__ void scan_kernel(const int* __restrict__ cnt, int* __restrict__ rowptr,
                            int* __restrict__ cursor) {
    __shared__ int ssum[1024];
    const int CH = (NNODES + 1023) / 1024;
    int t = threadIdx.x;
    int base = t * CH;
    int local = 0;
    for (int i = 0; i < CH; ++i) {
        int idx = base + i;
        if (idx < NNODES) local += cnt[idx];
    }
    ssum[t] = local;
    __syncthreads();
    for (int o = 1; o < 1024; o <<= 1) {
        int vv = (t >= o) ? ssum[t - o] : 0;
        __syncthreads();
        ssum[t] += vv;
        __syncthreads();
    }
    int run = (t > 0) ? ssum[t - 1] : 0;
    for (int i = 0; i < CH; ++i) {
        int idx = base + i;
        if (idx < NNODES) {
            rowptr[idx] = run;
            cursor[idx] = run;
            run += cnt[idx];
        }
    }
    if (t == 1023) rowptr[NNODES] = ssum[1023];
}

__global__ void scatter_kernel(const int* __restrict__ ei, int* __restrict__ cursor,
                               int* __restrict__ col) {
    int e = blockIdx.x * blockDim.x + threadIdx.x;
    if (e >= NEDGES) return;
    int s = ei[e];
    int d = ei[NEDGES + e];
    int pos = atomicAdd(cursor + d, 1);
    col[pos] = s;
}

// ---------- fused 4x linear: q (f32), kv interleaved (f16), skip (f32) ----------
// kv row layout (per node, 2*DOUT halves): channel-quad g4 = j/4 owns
// halves [g4*8 .. g4*8+7] = [k_{4g4..4g4+3} | v_{4g4..4g4+3}], so a gather
// lane reads its k-quad AND v-quad in ONE 16B load.

template<int DIN, int DOUT>
__global__ void linear4_kernel(const float* __restrict__ x,
                               const float* __restrict__ Wq, const float* __restrict__ bq,
                               const float* __restrict__ Wk, const float* __restrict__ bk,
                               const float* __restrict__ Wv, const float* __restrict__ bv,
                               const float* __restrict__ Ws, const float* __restrict__ bs,
                               float* __restrict__ q, __half* __restrict__ kv,
                               float* __restrict__ s) {
    __shared__ float sW[4][DIN * DOUT];
    __shared__ float sB[4][DOUT];
    const float* Wp[4] = {Wq, Wk, Wv, Ws};
    const float* Bp[4] = {bq, bk, bv, bs};
    for (int m = 0; m < 4; ++m) {
        for (int i = threadIdx.x; i < DIN * DOUT; i += blockDim.x) sW[m][i] = Wp[m][i];
        for (int i = threadIdx.x; i < DOUT; i += blockDim.x) sB[m][i] = Bp[m][i];
    }
    __syncthreads();
    int n = blockIdx.x * blockDim.x + threadIdx.x;
    if (n >= NNODES) return;

    float xr[DIN];
    #pragma unroll
    for (int i = 0; i < DIN; ++i) xr[i] = x[(size_t)n * DIN + i];

    // m=0 -> q (f32), m=1 -> k (f16, interleaved), m=2 -> v (f16, interleaved),
    // m=3 -> skip (f32)
    #pragma unroll
    for (int m = 0; m < 4; ++m) {
        #pragma unroll
        for (int j = 0; j < DOUT; j += 4) {
            float4 acc = make_float4(sB[m][j], sB[m][j + 1], sB[m][j + 2], sB[m][j + 3]);
            #pragma unroll
            for (int i = 0; i < DIN; ++i) {
                float xv = xr[i];
                acc.x += xv * sW[m][i * DOUT + j];
                acc.y += xv * sW[m][i * DOUT + j + 1];
                acc.z += xv * sW[m][i * DOUT + j + 2];
                acc.w += xv * sW[m][i * DOUT + j + 3];
            }
            if (m == 0) {
                *(float4*)(q + (size_t)n * DOUT + j) = acc;
            } else if (m == 3) {
                *(float4*)(s + (size_t)n * DOUT + j) = acc;
            } else {
                // interleaved: quad j/4 at row offset (j/4)*8, k at +0, v at +4
                __half* op = kv + (size_t)n * 2 * DOUT + (size_t)(j >> 2) * 8
                           + (m == 1 ? 0 : 4);
                *(__half2*)(op)     = __floats2half2_rn(acc.x, acc.y);
                *(__half2*)(op + 2) = __floats2half2_rn(acc.z, acc.w);
            }
        }
    }
}

// ---------- gather attention: persistent waves, 2-stage pipelined setup ----------
// Each wave grid-strides over node PAIRS. While computing pair p it has
// already issued rowptr loads for p+2W and colv/q loads for p+W, so the
// 3-trip serial setup chain (rowptr -> col -> q) is off the critical path.
// Compute body identical to the proven 2-node/wave kernel: LPE=D/4
// lanes/edge, interleaved fp16 kv, one 16B dwordx4 per edge-lane.

template<int D, bool POOL>
__global__ __launch_bounds__(256) void gather_attn_kernel(
    const int* __restrict__ rowptr, const int* __restrict__ col,
    const float* __restrict__ q, const __half* __restrict__ kv,
    const float* __restrict__ sk, const int* __restrict__ batch,
    float* __restrict__ out, float* __restrict__ pool, float* __restrict__ counts) {
    constexpr int LPE = D / 4;        // lanes per edge
    constexpr int G = 64 / LPE;       // edges per iteration
    constexpr float scale = (D == 16) ? 0.25f : 0.17677669529663687f;
    const int NP = NNODES / 2;        // node pairs
    const int W = gridDim.x * 4;      // total waves
    int wave = blockIdx.x * 4 + (threadIdx.x >> 6);
    if (wave >= NP) return;
    int lane = threadIdx.x & 63;
    int l = lane & (LPE - 1);         // channel-quad id
    int g = lane / LPE;               // edge-group id

    // ---- prologue: current pair p ----
    int p = wave;
    int cn0 = 2 * p;
    int c_rs0 = rowptr[cn0], c_mid = rowptr[cn0 + 1], c_re = rowptr[cn0 + 2];
    int c_d0 = c_mid - c_rs0, c_d1 = c_re - c_mid;
    int c_cv0 = (lane < min(c_d0, 64)) ? col[c_rs0 + lane] : 0;
    int c_cv1 = (lane < min(c_d1, 64)) ? col[c_mid + lane] : 0;
    float4 c_q0 = *(const float4*)(q + (size_t)cn0 * D + 4 * l);
    float4 c_q1 = *(const float4*)(q + (size_t)(cn0 + 1) * D + 4 * l);
    // rowptr for pair p+W (clamped; dead data when out of range)
    int pn = (p + W < NP) ? p + W : p;
    int n_rs0 = rowptr[2 * pn], n_mid = rowptr[2 * pn + 1], n_re = rowptr[2 * pn + 2];

    for (; p < NP; p += W) {
        // stage A: issue rowptr for p+2W
        int pf = (p + 2 * W < NP) ? p + 2 * W : p;
        int f_rs0 = rowptr[2 * pf], f_mid = rowptr[2 * pf + 1], f_re = rowptr[2 * pf + 2];
        // stage B: issue colv + q for p+W (its rowptr arrived last iteration)
        int pnc = (p + W < NP) ? p + W : p;
        int nn0 = 2 * pnc;
        int n_d0 = n_mid - n_rs0, n_d1 = n_re - n_mid;
        int n_cv0 = (lane < min(n_d0, 64)) ? col[n_rs0 + lane] : 0;
        int n_cv1 = (lane < min(n_d1, 64)) ? col[n_mid + lane] : 0;
        float4 n_q0 = *(const float4*)(q + (size_t)nn0 * D + 4 * l);
        float4 n_q1 = *(const float4*)(q + (size_t)(nn0 + 1) * D + 4 * l);

        // ---- compute current pair ----
        int n0 = 2 * p, n1 = n0 + 1;
        float m0 = -INFINITY, den0 = 0.0f, m1 = -INFINITY, den1 = 0.0f;
        float4 A0 = make_float4(0.0f, 0.0f, 0.0f, 0.0f);
        float4 A1 = make_float4(0.0f, 0.0f, 0.0f, 0.0f);
        int degmax = max(c_d0, c_d1);
        for (int off = 0; off < degmax; off += 64) {
            int na0 = min(c_d0 - off, 64);
            int na1 = min(c_d1 - off, 64);
            int cv0, cv1;
            if (off == 0) { cv0 = c_cv0; cv1 = c_cv1; }
            else {
                cv0 = (lane < na0) ? col[c_rs0 + off + lane] : 0;
                cv1 = (lane < na1) ? col[c_mid + off + lane] : 0;
            }
            int namax = max(na0, na1);
            int iters = (namax + G - 1) / G;
            for (int it = 0; it < iters; ++it) {
                int slot = it * G + g;
                int src0 = __shfl(cv0, slot, 64);
                int src1 = __shfl(cv1, slot, 64);
                uint4 r0 = *(const uint4*)(kv + (size_t)src0 * (2 * D) + 8 * l);
                uint4 r1 = *(const uint4*)(kv + (size_t)src1 * (2 * D) + 8 * l);
                bool act0 = slot < na0;
                bool act1 = slot < na1;
                float2 k01a = __half22float2(*(__half2*)&r0.x);
                float2 k23a = __half22float2(*(__half2*)&r0.y);
                float2 v01a = __half22float2(*(__half2*)&r0.z);
                float2 v23a = __half22float2(*(__half2*)&r0.w);
                float2 k01b = __half22float2(*(__half2*)&r1.x);
                float2 k23b = __half22float2(*(__half2*)&r1.y);
                float2 v01b = __half22float2(*(__half2*)&r1.z);
                float2 v23b = __half22float2(*(__half2*)&r1.w);
                float p0 = c_q0.x * k01a.x + c_q0.y * k01a.y + c_q0.z * k23a.x + c_q0.w * k23a.y;
                float p1 = c_q1.x * k01b.x + c_q1.y * k01b.y + c_q1.z * k23b.x + c_q1.w * k23b.y;
                #pragma unroll
                for (int o = 1; o < LPE; o <<= 1) {
                    p0 += __shfl_xor(p0, o, 64);
                    p1 += __shfl_xor(p1, o, 64);
                }
                {
                    float sc = act0 ? p0 * scale : -INFINITY;
                    float mn = fmaxf(m0, sc);
                    float r = (mn > m0) ? __expf(m0 - mn) : 1.0f;
                    float w = act0 ? __expf(sc - mn) : 0.0f;
                    m0 = mn;
                    den0 = den0 * r + w;
                    A0.x = A0.x * r + w * v01a.x;
                    A0.y = A0.y * r + w * v01a.y;
                    A0.z = A0.z * r + w * v23a.x;
                    A0.w = A0.w * r + w * v23a.y;
                }
                {
                    float sc = act1 ? p1 * scale : -INFINITY;
                    float mn = fmaxf(m1, sc);
                    float r = (mn > m1) ? __expf(m1 - mn) : 1.0f;
                    float w = act1 ? __expf(sc - mn) : 0.0f;
                    m1 = mn;
                    den1 = den1 * r + w;
                    A1.x = A1.x * r + w * v01b.x;
                    A1.y = A1.y * r + w * v01b.y;
                    A1.z = A1.z * r + w * v23b.x;
                    A1.w = A1.w * r + w * v23b.y;
                }
            }
        }

        // combine the G edge-groups across lane strides LPE..32, both nodes
        #pragma unroll
        for (int o = LPE; o < 64; o <<= 1) {
            float mo0 = __shfl_xor(m0, o, 64);
            float mo1 = __shfl_xor(m1, o, 64);
            float M0 = fmaxf(m0, mo0);
            float M1 = fmaxf(m1, mo1);
            float r0 = (m0 > -INFINITY) ? __expf(m0 - M0) : 0.0f;
            float r1 = (m1 > -INFINITY) ? __expf(m1 - M1) : 0.0f;
            float ds0 = den0 * r0, ds1 = den1 * r1;
            float a0x = A0.x * r0, a0y = A0.y * r0, a0z = A0.z * r0, a0w = A0.w * r0;
            float a1x = A1.x * r1, a1y = A1.y * r1, a1z = A1.z * r1, a1w = A1.w * r1;
            den0 = ds0 + __shfl_xor(ds0, o, 64);
            den1 = ds1 + __shfl_xor(ds1, o, 64);
            A0.x = a0x + __shfl_xor(a0x, o, 64);
            A0.y = a0y + __shfl_xor(a0y, o, 64);
            A0.z = a0z + __shfl_xor(a0z, o, 64);
            A0.w = a0w + __shfl_xor(a0w, o, 64);
            A1.x = a1x + __shfl_xor(a1x, o, 64);
            A1.y = a1y + __shfl_xor(a1y, o, 64);
            A1.z = a1z + __shfl_xor(a1z, o, 64);
            A1.w = a1w + __shfl_xor(a1w, o, 64);
            m0 = M0;
            m1 = M1;
        }

        if (g == 0) {
            float inv0 = 1.0f / fmaxf(den0, 1e-16f);
            float inv1 = 1.0f / fmaxf(den1, 1e-16f);
            float4 s0 = *(const float4*)(sk + (size_t)n0 * D + 4 * l);
            float4 s1 = *(const float4*)(sk + (size_t)n1 * D + 4 * l);
            float4 o0, o1;
            o0.x = fmaxf(A0.x * inv0 + s0.x, 0.0f);
            o0.y = fmaxf(A0.y * inv0 + s0.y, 0.0f);
            o0.z = fmaxf(A0.z * inv0 + s0.z, 0.0f);
            o0.w = fmaxf(A0.w * inv0 + s0.w, 0.0f);
            o1.x = fmaxf(A1.x * inv1 + s1.x, 0.0f);
            o1.y = fmaxf(A1.y * inv1 + s1.y, 0.0f);
            o1.z = fmaxf(A1.z * inv1 + s1.z, 0.0f);
            o1.w = fmaxf(A1.w * inv1 + s1.w, 0.0f);
            if (POOL) {
                int b0 = batch[n0];
                int b1 = batch[n1];
                atomicAdd(pool + (size_t)b0 * D + 4 * l + 0, o0.x);
                atomicAdd(pool + (size_t)b0 * D + 4 * l + 1, o0.y);
                atomicAdd(pool + (size_t)b0 * D + 4 * l + 2, o0.z);
                atomicAdd(pool + (size_t)b0 * D + 4 * l + 3, o0.w);
                atomicAdd(pool + (size_t)b1 * D + 4 * l + 0, o1.x);
                atomicAdd(pool + (size_t)b1 * D + 4 * l + 1, o1.y);
                atomicAdd(pool + (size_t)b1 * D + 4 * l + 2, o1.z);
                atomicAdd(pool + (size_t)b1 * D + 4 * l + 3, o1.w);
                if (l == 0) {
                    atomicAdd(counts + b0, 1.0f);
                    atomicAdd(counts + b1, 1.0f);
                }
            } else {
                *(float4*)(out + (size_t)n0 * D + 4 * l) = o0;
                *(float4*)(out + (size_t)n1 * D + 4 * l) = o1;
            }
        }

        // rotate pipeline registers
        c_rs0 = n_rs0; c_mid = n_mid;
        c_d0 = n_d0; c_d1 = n_d1;
        c_cv0 = n_cv0; c_cv1 = n_cv1;
        c_q0 = n_q0; c_q1 = n_q1;
        n_rs0 = f_rs0; n_mid = f_mid; n_re = f_re;
    }
}

// ---------- FC head ----------

__global__ void final_fc_kernel(const float* __restrict__ pool,
                                const float* __restrict__ counts,
                                const float* __restrict__ Wfc1, const float* __restrict__ bfc1,
                                const float* __restrict__ Wfc2, const float* __restrict__ bfc2,
                                float* __restrict__ out) {
    __shared__ float sW1[32 * 64];
    __shared__ float sB1[64];
    __shared__ float sW2[64];
    for (int i = threadIdx.x; i < 32 * 64; i += blockDim.x) sW1[i] = Wfc1[i];
    for (int i = threadIdx.x; i < 64; i += blockDim.x) { sB1[i] = bfc1[i]; sW2[i] = Wfc2[i]; }
    __syncthreads();
    int g = blockIdx.x * blockDim.x + threadIdx.x;
    if (g >= NGRAPHS) return;
    float c = fmaxf(counts[g], 1.0f);
    float gv[32];
    #pragma unroll
    for (int i = 0; i < 32; ++i) gv[i] = pool[(size_t)g * 32 + i] / c;
    float acc2 = bfc2[0];
    #pragma unroll
    for (int j = 0; j < 64; ++j) {
        float h = sB1[j];
        #pragma unroll
        for (int i = 0; i < 32; ++i) h += gv[i] * sW1[i * 64 + j];
        acc2 += fmaxf(h, 0.0f) * sW2[j];
    }
    out[g] = acc2;
}

// ---------- launch ----------

extern "C" void kernel_launch(void* const* d_in, const int* in_sizes, int n_in,
                              void* d_out, int out_size, void* d_ws, size_t ws_size,
                              hipStream_t stream) {
    const float* x     = (const float*)d_in[0];
    const int*   ei    = (const int*)d_in[1];
    const int*   batch = (const int*)d_in[2];
    const float* Wq1 = (const float*)d_in[3];  const float* bq1 = (const float*)d_in[4];
    const float* Wk1 = (const float*)d_in[5];  const float* bk1 = (const float*)d_in[6];
    const float* Wv1 = (const float*)d_in[7];  const float* bv1 = (const float*)d_in[8];
    const float* Ws1 = (const float*)d_in[9];  const float* bs1 = (const float*)d_in[10];
    const float* Wq2 = (const float*)d_in[11]; const float* bq2 = (const float*)d_in[12];
    const float* Wk2 = (const float*)d_in[13]; const float* bk2 = (const float*)d_in[14];
    const float* Wv2 = (const float*)d_in[15]; const float* bv2 = (const float*)d_in[16];
    const float* Ws2 = (const float*)d_in[17]; const float* bs2 = (const float*)d_in[18];
    const float* Wfc1 = (const float*)d_in[19]; const float* bfc1 = (const float*)d_in[20];
    const float* Wfc2 = (const float*)d_in[21]; const float* bfc2 = (const float*)d_in[22];
    float* out = (float*)d_out;

    char* wsb = (char*)d_ws;
    size_t off = 0;
    auto alloc = [&](size_t bytes) {
        void* p = wsb + off;
        off += (bytes + 255) & ~(size_t)255;
        return p;
    };
    float*  q      = (float*)alloc((size_t)NNODES * 32 * 4);
    __half* kv     = (__half*)alloc((size_t)NNODES * 64 * 2);  // interleaved k|v quads, fp16
    float*  sk     = (float*)alloc((size_t)NNODES * 32 * 4);
    float*  h1     = (float*)alloc((size_t)NNODES * 16 * 4);
    int*    cnt    = (int*)alloc((size_t)NNODES * 4);
    int*    rowptr = (int*)alloc((size_t)(NNODES + 1) * 4);
    int*    cursor = (int*)alloc((size_t)NNODES * 4);
    int*    col    = (int*)alloc((size_t)NEDGES * 4);
    float*  pool   = (float*)alloc((size_t)NGRAPHS * 32 * 4);
    float*  counts = (float*)alloc((size_t)NGRAPHS * 4);

    const int B = 256;
    const int gridN = (NNODES + B - 1) / B;
    const int gridE = (NEDGES + B - 1) / B;
    const int gridP = 2048;   // persistent: 8 blocks/CU, grid-stride over pairs

    // ----- CSR build (by destination), shared by both layers -----
    csr_init_kernel<<<gridN, B, 0, stream>>>(cnt, pool, counts);
    count_deg_kernel<<<gridE, B, 0, stream>>>(ei, cnt);
    scan_kernel<<<1, 1024, 0, stream>>>(cnt, rowptr, cursor);
    scatter_kernel<<<gridE, B, 0, stream>>>(ei, cursor, col);

    // ----- layer 1 (d=16) -----
    linear4_kernel<11, 16><<<gridN, B, 0, stream>>>(x, Wq1, bq1, Wk1, bk1, Wv1, bv1, Ws1, bs1,
                                                    q, kv, sk);
    gather_attn_kernel<16, false><<<gridP, B, 0, stream>>>(rowptr, col, q, kv, sk, batch,
                                                           h1, nullptr, nullptr);

    // ----- layer 2 (d=32) -----
    linear4_kernel<16, 32><<<gridN, B, 0, stream>>>(h1, Wq2, bq2, Wk2, bk2, Wv2, bv2, Ws2, bs2,
                                                    q, kv, sk);
    gather_attn_kernel<32, true><<<gridP, B, 0, stream>>>(rowptr, col, q, kv, sk, batch,
                                                          nullptr, pool, counts);

    // ----- head -----
    final_fc_kernel<<<1, 512, 0, stream>>>(pool, counts, Wfc1, bfc1, Wfc2, bfc2, out);
}

// Round 8
// 698.616 us; speedup vs baseline: 1.6047x; 1.4546x over previous
//
#include <hip/hip_runtime.h>
#include <hip/hip_fp16.h>
#include <math.h>

#define NNODES 100000
#define NEDGES 3200000
#define NGRAPHS 512

// ---------- CSR build (single-atomic-pass counting sort) ----------

__global__ void csr_init_kernel(int* __restrict__ cnt,
                                float* __restrict__ pool, float* __restrict__ counts) {
    int i = blockIdx.x * blockDim.x + threadIdx.x;
    if (i < NNODES) cnt[i] = 0;
    if (i < NGRAPHS * 32) pool[i] = 0.0f;
    if (i < NGRAPHS) counts[i] = 0.0f;
}

// pass 1: count degrees AND record each edge's rank within its dst.
// This is the ONLY atomic pass (the old scatter paid the atomic floor again).
__global__ void count_rank_kernel(const int* __restrict__ ei,
                                  int* __restrict__ cnt, int* __restrict__ rank) {
    int e = blockIdx.x * blockDim.x + threadIdx.x;
    if (e >= NEDGES) return;
    int d = ei[NEDGES + e];
    rank[e] = atomicAdd(cnt + d, 1);   // rank store is coalesced
}

__global__ void scan_kernel(const int* __restrict__ cnt, int* __restrict__ rowptr) {
    __shared__ int ssum[1024];
    const int CH = (NNODES + 1023) / 1024;
    int t = threadIdx.x;
    int base = t * CH;
    int local = 0;
    for (int i = 0; i < CH; ++i) {
        int idx = base + i;
        if (idx < NNODES) local += cnt[idx];
    }
    ssum[t] = local;
    __syncthreads();
    for (int o = 1; o < 1024; o <<= 1) {
        int vv = (t >= o) ? ssum[t - o] : 0;
        __syncthreads();
        ssum[t] += vv;
        __syncthreads();
    }
    int run = (t > 0) ? ssum[t - 1] : 0;
    for (int i = 0; i < CH; ++i) {
        int idx = base + i;
        if (idx < NNODES) {
            rowptr[idx] = run;
            run += cnt[idx];
        }
    }
    if (t == 1023) rowptr[NNODES] = ssum[1023];
}

// pass 2: atomic-free placement. Random rowptr[d] read (MLP-friendly) +
// fire-and-forget random store — ordinary load/store path, not the atomic pipe.
__global__ void place_kernel(const int* __restrict__ ei, const int* __restrict__ rowptr,
                             const int* __restrict__ rank, int* __restrict__ col) {
    int e = blockIdx.x * blockDim.x + threadIdx.x;
    if (e >= NEDGES) return;
    int s = ei[e];
    int d = ei[NEDGES + e];
    col[rowptr[d] + rank[e]] = s;
}

// ---------- fused 4x linear: q (f32), kv interleaved (f16), skip (f32) ----------
// kv row layout (per node, 2*DOUT halves): channel-quad g4 = j/4 owns
// halves [g4*8 .. g4*8+7] = [k_{4g4..4g4+3} | v_{4g4..4g4+3}], so a gather
// lane reads its k-quad AND v-quad in ONE 16B load.

template<int DIN, int DOUT>
__global__ void linear4_kernel(const float* __restrict__ x,
                               const float* __restrict__ Wq, const float* __restrict__ bq,
                               const float* __restrict__ Wk, const float* __restrict__ bk,
                               const float* __restrict__ Wv, const float* __restrict__ bv,
                               const float* __restrict__ Ws, const float* __restrict__ bs,
                               float* __restrict__ q, __half* __restrict__ kv,
                               float* __restrict__ s) {
    __shared__ float sW[4][DIN * DOUT];
    __shared__ float sB[4][DOUT];
    const float* Wp[4] = {Wq, Wk, Wv, Ws};
    const float* Bp[4] = {bq, bk, bv, bs};
    for (int m = 0; m < 4; ++m) {
        for (int i = threadIdx.x; i < DIN * DOUT; i += blockDim.x) sW[m][i] = Wp[m][i];
        for (int i = threadIdx.x; i < DOUT; i += blockDim.x) sB[m][i] = Bp[m][i];
    }
    __syncthreads();
    int n = blockIdx.x * blockDim.x + threadIdx.x;
    if (n >= NNODES) return;

    float xr[DIN];
    #pragma unroll
    for (int i = 0; i < DIN; ++i) xr[i] = x[(size_t)n * DIN + i];

    // m=0 -> q (f32), m=1 -> k (f16, interleaved), m=2 -> v (f16, interleaved),
    // m=3 -> skip (f32)
    #pragma unroll
    for (int m = 0; m < 4; ++m) {
        #pragma unroll
        for (int j = 0; j < DOUT; j += 4) {
            float4 acc = make_float4(sB[m][j], sB[m][j + 1], sB[m][j + 2], sB[m][j + 3]);
            #pragma unroll
            for (int i = 0; i < DIN; ++i) {
                float xv = xr[i];
                acc.x += xv * sW[m][i * DOUT + j];
                acc.y += xv * sW[m][i * DOUT + j + 1];
                acc.z += xv * sW[m][i * DOUT + j + 2];
                acc.w += xv * sW[m][i * DOUT + j + 3];
            }
            if (m == 0) {
                *(float4*)(q + (size_t)n * DOUT + j) = acc;
            } else if (m == 3) {
                *(float4*)(s + (size_t)n * DOUT + j) = acc;
            } else {
                // interleaved: quad j/4 at row offset (j/4)*8, k at +0, v at +4
                __half* op = kv + (size_t)n * 2 * DOUT + (size_t)(j >> 2) * 8
                           + (m == 1 ? 0 : 4);
                *(__half2*)(op)     = __floats2half2_rn(acc.x, acc.y);
                *(__half2*)(op + 2) = __floats2half2_rn(acc.z, acc.w);
            }
        }
    }
}

// ---------- gather attention: persistent waves, 2-stage pipelined setup ----------
// Each wave grid-strides over node PAIRS. While computing pair p it has
// already issued rowptr loads for p+2W and colv/q loads for p+W, so the
// 3-trip serial setup chain (rowptr -> col -> q) is off the critical path.

template<int D, bool POOL>
__global__ __launch_bounds__(256) void gather_attn_kernel(
    const int* __restrict__ rowptr, const int* __restrict__ col,
    const float* __restrict__ q, const __half* __restrict__ kv,
    const float* __restrict__ sk, const int* __restrict__ batch,
    float* __restrict__ out, float* __restrict__ pool, float* __restrict__ counts) {
    constexpr int LPE = D / 4;        // lanes per edge
    constexpr int G = 64 / LPE;       // edges per iteration
    constexpr float scale = (D == 16) ? 0.25f : 0.17677669529663687f;
    const int NP = NNODES / 2;        // node pairs
    const int W = gridDim.x * 4;      // total waves
    int wave = blockIdx.x * 4 + (threadIdx.x >> 6);
    if (wave >= NP) return;
    int lane = threadIdx.x & 63;
    int l = lane & (LPE - 1);         // channel-quad id
    int g = lane / LPE;               // edge-group id

    // ---- prologue: current pair p ----
    int p = wave;
    int cn0 = 2 * p;
    int c_rs0 = rowptr[cn0], c_mid = rowptr[cn0 + 1], c_re = rowptr[cn0 + 2];
    int c_d0 = c_mid - c_rs0, c_d1 = c_re - c_mid;
    int c_cv0 = (lane < min(c_d0, 64)) ? col[c_rs0 + lane] : 0;
    int c_cv1 = (lane < min(c_d1, 64)) ? col[c_mid + lane] : 0;
    float4 c_q0 = *(const float4*)(q + (size_t)cn0 * D + 4 * l);
    float4 c_q1 = *(const float4*)(q + (size_t)(cn0 + 1) * D + 4 * l);
    // rowptr for pair p+W (clamped; dead data when out of range)
    int pn = (p + W < NP) ? p + W : p;
    int n_rs0 = rowptr[2 * pn], n_mid = rowptr[2 * pn + 1], n_re = rowptr[2 * pn + 2];

    for (; p < NP; p += W) {
        // stage A: issue rowptr for p+2W
        int pf = (p + 2 * W < NP) ? p + 2 * W : p;
        int f_rs0 = rowptr[2 * pf], f_mid = rowptr[2 * pf + 1], f_re = rowptr[2 * pf + 2];
        // stage B: issue colv + q for p+W (its rowptr arrived last iteration)
        int pnc = (p + W < NP) ? p + W : p;
        int nn0 = 2 * pnc;
        int n_d0 = n_mid - n_rs0, n_d1 = n_re - n_mid;
        int n_cv0 = (lane < min(n_d0, 64)) ? col[n_rs0 + lane] : 0;
        int n_cv1 = (lane < min(n_d1, 64)) ? col[n_mid + lane] : 0;
        float4 n_q0 = *(const float4*)(q + (size_t)nn0 * D + 4 * l);
        float4 n_q1 = *(const float4*)(q + (size_t)(nn0 + 1) * D + 4 * l);

        // ---- compute current pair ----
        int n0 = 2 * p, n1 = n0 + 1;
        float m0 = -INFINITY, den0 = 0.0f, m1 = -INFINITY, den1 = 0.0f;
        float4 A0 = make_float4(0.0f, 0.0f, 0.0f, 0.0f);
        float4 A1 = make_float4(0.0f, 0.0f, 0.0f, 0.0f);
        int degmax = max(c_d0, c_d1);
        for (int off = 0; off < degmax; off += 64) {
            int na0 = min(c_d0 - off, 64);
            int na1 = min(c_d1 - off, 64);
            int cv0, cv1;
            if (off == 0) { cv0 = c_cv0; cv1 = c_cv1; }
            else {
                cv0 = (lane < na0) ? col[c_rs0 + off + lane] : 0;
                cv1 = (lane < na1) ? col[c_mid + off + lane] : 0;
            }
            int namax = max(na0, na1);
            int iters = (namax + G - 1) / G;
            for (int it = 0; it < iters; ++it) {
                int slot = it * G + g;
                int src0 = __shfl(cv0, slot, 64);
                int src1 = __shfl(cv1, slot, 64);
                uint4 r0 = *(const uint4*)(kv + (size_t)src0 * (2 * D) + 8 * l);
                uint4 r1 = *(const uint4*)(kv + (size_t)src1 * (2 * D) + 8 * l);
                bool act0 = slot < na0;
                bool act1 = slot < na1;
                float2 k01a = __half22float2(*(__half2*)&r0.x);
                float2 k23a = __half22float2(*(__half2*)&r0.y);
                float2 v01a = __half22float2(*(__half2*)&r0.z);
                float2 v23a = __half22float2(*(__half2*)&r0.w);
                float2 k01b = __half22float2(*(__half2*)&r1.x);
                float2 k23b = __half22float2(*(__half2*)&r1.y);
                float2 v01b = __half22float2(*(__half2*)&r1.z);
                float2 v23b = __half22float2(*(__half2*)&r1.w);
                float p0 = c_q0.x * k01a.x + c_q0.y * k01a.y + c_q0.z * k23a.x + c_q0.w * k23a.y;
                float p1 = c_q1.x * k01b.x + c_q1.y * k01b.y + c_q1.z * k23b.x + c_q1.w * k23b.y;
                #pragma unroll
                for (int o = 1; o < LPE; o <<= 1) {
                    p0 += __shfl_xor(p0, o, 64);
                    p1 += __shfl_xor(p1, o, 64);
                }
                {
                    float sc = act0 ? p0 * scale : -INFINITY;
                    float mn = fmaxf(m0, sc);
                    float r = (mn > m0) ? __expf(m0 - mn) : 1.0f;
                    float w = act0 ? __expf(sc - mn) : 0.0f;
                    m0 = mn;
                    den0 = den0 * r + w;
                    A0.x = A0.x * r + w * v01a.x;
                    A0.y = A0.y * r + w * v01a.y;
                    A0.z = A0.z * r + w * v23a.x;
                    A0.w = A0.w * r + w * v23a.y;
                }
                {
                    float sc = act1 ? p1 * scale : -INFINITY;
                    float mn = fmaxf(m1, sc);
                    float r = (mn > m1) ? __expf(m1 - mn) : 1.0f;
                    float w = act1 ? __expf(sc - mn) : 0.0f;
                    m1 = mn;
                    den1 = den1 * r + w;
                    A1.x = A1.x * r + w * v01b.x;
                    A1.y = A1.y * r + w * v01b.y;
                    A1.z = A1.z * r + w * v23b.x;
                    A1.w = A1.w * r + w * v23b.y;
                }
            }
        }

        // combine the G edge-groups across lane strides LPE..32, both nodes
        #pragma unroll
        for (int o = LPE; o < 64; o <<= 1) {
            float mo0 = __shfl_xor(m0, o, 64);
            float mo1 = __shfl_xor(m1, o, 64);
            float M0 = fmaxf(m0, mo0);
            float M1 = fmaxf(m1, mo1);
            float r0 = (m0 > -INFINITY) ? __expf(m0 - M0) : 0.0f;
            float r1 = (m1 > -INFINITY) ? __expf(m1 - M1) : 0.0f;
            float ds0 = den0 * r0, ds1 = den1 * r1;
            float a0x = A0.x * r0, a0y = A0.y * r0, a0z = A0.z * r0, a0w = A0.w * r0;
            float a1x = A1.x * r1, a1y = A1.y * r1, a1z = A1.z * r1, a1w = A1.w * r1;
            den0 = ds0 + __shfl_xor(ds0, o, 64);
            den1 = ds1 + __shfl_xor(ds1, o, 64);
            A0.x = a0x + __shfl_xor(a0x, o, 64);
            A0.y = a0y + __shfl_xor(a0y, o, 64);
            A0.z = a0z + __shfl_xor(a0z, o, 64);
            A0.w = a0w + __shfl_xor(a0w, o, 64);
            A1.x = a1x + __shfl_xor(a1x, o, 64);
            A1.y = a1y + __shfl_xor(a1y, o, 64);
            A1.z = a1z + __shfl_xor(a1z, o, 64);
            A1.w = a1w + __shfl_xor(a1w, o, 64);
            m0 = M0;
            m1 = M1;
        }

        if (g == 0) {
            float inv0 = 1.0f / fmaxf(den0, 1e-16f);
            float inv1 = 1.0f / fmaxf(den1, 1e-16f);
            float4 s0 = *(const float4*)(sk + (size_t)n0 * D + 4 * l);
            float4 s1 = *(const float4*)(sk + (size_t)n1 * D + 4 * l);
            float4 o0, o1;
            o0.x = fmaxf(A0.x * inv0 + s0.x, 0.0f);
            o0.y = fmaxf(A0.y * inv0 + s0.y, 0.0f);
            o0.z = fmaxf(A0.z * inv0 + s0.z, 0.0f);
            o0.w = fmaxf(A0.w * inv0 + s0.w, 0.0f);
            o1.x = fmaxf(A1.x * inv1 + s1.x, 0.0f);
            o1.y = fmaxf(A1.y * inv1 + s1.y, 0.0f);
            o1.z = fmaxf(A1.z * inv1 + s1.z, 0.0f);
            o1.w = fmaxf(A1.w * inv1 + s1.w, 0.0f);
            if (POOL) {
                int b0 = batch[n0];
                int b1 = batch[n1];
                atomicAdd(pool + (size_t)b0 * D + 4 * l + 0, o0.x);
                atomicAdd(pool + (size_t)b0 * D + 4 * l + 1, o0.y);
                atomicAdd(pool + (size_t)b0 * D + 4 * l + 2, o0.z);
                atomicAdd(pool + (size_t)b0 * D + 4 * l + 3, o0.w);
                atomicAdd(pool + (size_t)b1 * D + 4 * l + 0, o1.x);
                atomicAdd(pool + (size_t)b1 * D + 4 * l + 1, o1.y);
                atomicAdd(pool + (size_t)b1 * D + 4 * l + 2, o1.z);
                atomicAdd(pool + (size_t)b1 * D + 4 * l + 3, o1.w);
                if (l == 0) {
                    atomicAdd(counts + b0, 1.0f);
                    atomicAdd(counts + b1, 1.0f);
                }
            } else {
                *(float4*)(out + (size_t)n0 * D + 4 * l) = o0;
                *(float4*)(out + (size_t)n1 * D + 4 * l) = o1;
            }
        }

        // rotate pipeline registers
        c_rs0 = n_rs0; c_mid = n_mid;
        c_d0 = n_d0; c_d1 = n_d1;
        c_cv0 = n_cv0; c_cv1 = n_cv1;
        c_q0 = n_q0; c_q1 = n_q1;
        n_rs0 = f_rs0; n_mid = f_mid; n_re = f_re;
    }
}

// ---------- FC head ----------

__global__ void final_fc_kernel(const float* __restrict__ pool,
                                const float* __restrict__ counts,
                                const float* __restrict__ Wfc1, const float* __restrict__ bfc1,
                                const float* __restrict__ Wfc2, const float* __restrict__ bfc2,
                                float* __restrict__ out) {
    __shared__ float sW1[32 * 64];
    __shared__ float sB1[64];
    __shared__ float sW2[64];
    for (int i = threadIdx.x; i < 32 * 64; i += blockDim.x) sW1[i] = Wfc1[i];
    for (int i = threadIdx.x; i < 64; i += blockDim.x) { sB1[i] = bfc1[i]; sW2[i] = Wfc2[i]; }
    __syncthreads();
    int g = blockIdx.x * blockDim.x + threadIdx.x;
    if (g >= NGRAPHS) return;
    float c = fmaxf(counts[g], 1.0f);
    float gv[32];
    #pragma unroll
    for (int i = 0; i < 32; ++i) gv[i] = pool[(size_t)g * 32 + i] / c;
    float acc2 = bfc2[0];
    #pragma unroll
    for (int j = 0; j < 64; ++j) {
        float h = sB1[j];
        #pragma unroll
        for (int i = 0; i < 32; ++i) h += gv[i] * sW1[i * 64 + j];
        acc2 += fmaxf(h, 0.0f) * sW2[j];
    }
    out[g] = acc2;
}

// ---------- launch ----------

extern "C" void kernel_launch(void* const* d_in, const int* in_sizes, int n_in,
                              void* d_out, int out_size, void* d_ws, size_t ws_size,
                              hipStream_t stream) {
    const float* x     = (const float*)d_in[0];
    const int*   ei    = (const int*)d_in[1];
    const int*   batch = (const int*)d_in[2];
    const float* Wq1 = (const float*)d_in[3];  const float* bq1 = (const float*)d_in[4];
    const float* Wk1 = (const float*)d_in[5];  const float* bk1 = (const float*)d_in[6];
    const float* Wv1 = (const float*)d_in[7];  const float* bv1 = (const float*)d_in[8];
    const float* Ws1 = (const float*)d_in[9];  const float* bs1 = (const float*)d_in[10];
    const float* Wq2 = (const float*)d_in[11]; const float* bq2 = (const float*)d_in[12];
    const float* Wk2 = (const float*)d_in[13]; const float* bk2 = (const float*)d_in[14];
    const float* Wv2 = (const float*)d_in[15]; const float* bv2 = (const float*)d_in[16];
    const float* Ws2 = (const float*)d_in[17]; const float* bs2 = (const float*)d_in[18];
    const float* Wfc1 = (const float*)d_in[19]; const float* bfc1 = (const float*)d_in[20];
    const float* Wfc2 = (const float*)d_in[21]; const float* bfc2 = (const float*)d_in[22];
    float* out = (float*)d_out;

    char* wsb = (char*)d_ws;
    size_t off = 0;
    auto alloc = [&](size_t bytes) {
        void* p = wsb + off;
        off += (bytes + 255) & ~(size_t)255;
        return p;
    };
    float*  q      = (float*)alloc((size_t)NNODES * 32 * 4);
    __half* kv     = (__half*)alloc((size_t)NNODES * 64 * 2);  // interleaved k|v quads, fp16
    float*  sk     = (float*)alloc((size_t)NNODES * 32 * 4);
    float*  h1     = (float*)alloc((size_t)NNODES * 16 * 4);
    int*    cnt    = (int*)alloc((size_t)NNODES * 4);
    int*    rowptr = (int*)alloc((size_t)(NNODES + 1) * 4);
    int*    rank   = (int*)alloc((size_t)NEDGES * 4);
    int*    col    = (int*)alloc((size_t)NEDGES * 4);
    float*  pool   = (float*)alloc((size_t)NGRAPHS * 32 * 4);
    float*  counts = (float*)alloc((size_t)NGRAPHS * 4);

    const int B = 256;
    const int gridN = (NNODES + B - 1) / B;
    const int gridE = (NEDGES + B - 1) / B;
    const int gridP = 2048;   // persistent: 8 blocks/CU, grid-stride over pairs

    // ----- CSR build (by destination), single atomic pass -----
    csr_init_kernel<<<gridN, B, 0, stream>>>(cnt, pool, counts);
    count_rank_kernel<<<gridE, B, 0, stream>>>(ei, cnt, rank);
    scan_kernel<<<1, 1024, 0, stream>>>(cnt, rowptr);
    place_kernel<<<gridE, B, 0, stream>>>(ei, rowptr, rank, col);

    // ----- layer 1 (d=16) -----
    linear4_kernel<11, 16><<<gridN, B, 0, stream>>>(x, Wq1, bq1, Wk1, bk1, Wv1, bv1, Ws1, bs1,
                                                    q, kv, sk);
    gather_attn_kernel<16, false><<<gridP, B, 0, stream>>>(rowptr, col, q, kv, sk, batch,
                                                           h1, nullptr, nullptr);

    // ----- layer 2 (d=32) -----
    linear4_kernel<16, 32><<<gridN, B, 0, stream>>>(h1, Wq2, bq2, Wk2, bk2, Wv2, bv2, Ws2, bs2,
                                                    q, kv, sk);
    gather_attn_kernel<32, true><<<gridP, B, 0, stream>>>(rowptr, col, q, kv, sk, batch,
                                                          nullptr, pool, counts);

    // ----- head -----
    final_fc_kernel<<<1, 512, 0, stream>>>(pool, counts, Wfc1, bfc1, Wfc2, bfc2, out);
}